// Round 9
// baseline (421.468 us; speedup 1.0000x reference)
//
#include <hip/hip_runtime.h>
#include <hip/hip_fp16.h>

typedef _Float16 f16x8 __attribute__((ext_vector_type(8)));
typedef _Float16 f16x4 __attribute__((ext_vector_type(4)));
typedef float f32x4 __attribute__((ext_vector_type(4)));

#define NB 32
#define NK 64
#define ND 4
#define NH 512
#define NKP 544   // node-input K (520) padded to 17*32

// ---------------------------------------------------------------- prep ----

__global__ void prep_obs_kernel(const float* __restrict__ obs,
                                const float* __restrict__ state,
                                float* __restrict__ o,
                                float* __restrict__ maskp,
                                float* __restrict__ cntp,
                                _Float16* __restrict__ nodein) {
  const int b = blockIdx.x;
  const int j = threadIdx.x;  // 64
  float o0 = obs[(b*4 + 0)*64 + j];
  float o1 = obs[(b*4 + 1)*64 + j];
  float o2 = obs[(b*4 + 2)*64 + j];
  float o3 = obs[(b*4 + 3)*64 + j];
  size_t bi = (size_t)b*64 + j;
  float* orow = o + bi*4;
  orow[0] = o0; orow[1] = o1; orow[2] = o2; orow[3] = o3;
  float s = fabsf(o0) + fabsf(o1) + fabsf(o2) + fabsf(o3);
  float m = (s != 0.0f) ? 1.0f : 0.0f;
  maskp[bi] = m;
  float c = m;
  #pragma unroll
  for (int off = 1; off < 64; off <<= 1) c += __shfl_xor(c, off);
  if (j == 0) cntp[b] = fmaxf(c, 1e-6f);
  _Float16* nrow = nodein + bi*NKP;
  nrow[0] = (_Float16)o0; nrow[1] = (_Float16)o1;
  nrow[2] = (_Float16)o2; nrow[3] = (_Float16)o3;
  nrow[516] = (_Float16)state[b*4 + 0];
  nrow[517] = (_Float16)state[b*4 + 1];
  nrow[518] = (_Float16)state[b*4 + 2];
  nrow[519] = (_Float16)state[b*4 + 3];
  for (int k2 = 520; k2 < 544; ++k2) nrow[k2] = (_Float16)0.0f;
}

// u16[bi][c] = W1[:, :4]·o_bi + b1  (f16);  v16[bi][c] = W1[:, 4:]·o_bi (f16)
__global__ void prep_uv16(const float* __restrict__ o,
                          const float* __restrict__ e1w,
                          const float* __restrict__ e1b,
                          _Float16* __restrict__ u16,
                          _Float16* __restrict__ v16) {
  const int bi = blockIdx.x;     // 2048
  const int c = threadIdx.x;     // 512
  const float* orow = o + (size_t)bi*4;
  float o0 = orow[0], o1 = orow[1], o2 = orow[2], o3 = orow[3];
  const float* wr = e1w + c*8;
  float u = wr[0]*o0 + wr[1]*o1 + wr[2]*o2 + wr[3]*o3 + e1b[c];
  float v = wr[4]*o0 + wr[5]*o1 + wr[6]*o2 + wr[7]*o3;
  u16[(size_t)bi*NH + c] = (_Float16)u;
  v16[(size_t)bi*NH + c] = (_Float16)v;
}

__global__ void prep_w16_kernel(const float* __restrict__ e2w,
                                const float* __restrict__ e3w,
                                const float* __restrict__ n2w,
                                const float* __restrict__ n1w,
                                _Float16* __restrict__ w2h,
                                _Float16* __restrict__ w3h,
                                _Float16* __restrict__ n2wh,
                                _Float16* __restrict__ n1wh) {
  int idx = blockIdx.x * blockDim.x + threadIdx.x;
  const int A = 512*512, Bc = 512*512, C = 256*512, Dn = 512*544;
  if (idx < A) {
    w2h[idx] = (_Float16)e2w[idx];
  } else if (idx < A + Bc) {
    int q = idx - A; w3h[q] = (_Float16)e3w[q];
  } else if (idx < A + Bc + C) {
    int q = idx - A - Bc; n2wh[q] = (_Float16)n2w[q];
  } else if (idx < A + Bc + C + Dn) {
    int q = idx - A - Bc - C;
    int n = q / 544, k = q % 544;
    n1wh[q] = (k < 520) ? (_Float16)n1w[n*520 + k] : (_Float16)0.0f;
  }
}

__global__ void prep_stfeat_kernel(const float* __restrict__ state,
                                   const float* __restrict__ lw,
                                   const float* __restrict__ lb,
                                   float* __restrict__ xfeat) {
  const int b = blockIdx.x, c = threadIdx.x;  // 512
  const float* s = state + b*4;
  const float* wr = lw + c*4;
  float hv = wr[0]*s[0] + wr[1]*s[1] + wr[2]*s[2] + wr[3]*s[3] + lb[c];
  xfeat[b*1024 + c] = fmaxf(hv, 0.0f);
}

// ----------------------------------------------------- edge (fused MLP) ----
// One WG = 128 edge rows = 2 (b,i) groups x 64 j. 1024 threads = 16 waves
// = 2 j-halves x 8 col-groups of 64 -> 4 waves/SIMD at 1 WG/CU.
// __launch_bounds__(1024, 2): VGPR budget 256 (NOT the (1024,4)=128 spill
// trap of R7). acc[4][4]=64 AGPR + ~80 VGPR, no spill.
// TRANSPOSED MFMA (R5/R6-refchecked): A = W rows (n, global/L2),
// B = H rows (j, LDS). D: n = lg*4+r (reg), j = lane&15.
// H: 8 k-tiles [128][64] f16 (R6 layout):
//   byte = (k>>6)*16384 + row*128 + ((k&63)*2 ^ ((row&7)<<4))

__device__ __forceinline__ void mlp_layer(const char* ldsb,
                                          const _Float16* __restrict__ wbase,
                                          const float* __restrict__ bias,
                                          int wcol, int wj, int lr, int lg,
                                          f32x4 acc[4][4]) {
  #pragma unroll
  for (int nt = 0; nt < 4; ++nt) {
    float4 bz = *(const float4*)(bias + wcol + nt*16 + lg*4);
    #pragma unroll
    for (int jt = 0; jt < 4; ++jt) {
      acc[nt][jt][0] = bz.x; acc[nt][jt][1] = bz.y;
      acc[nt][jt][2] = bz.z; acc[nt][jt][3] = bz.w;
    }
  }
  const _Float16* abase = wbase + (size_t)(wcol + lr)*NH + lg*8;
  f16x8 afp[4];
  #pragma unroll
  for (int nt = 0; nt < 4; ++nt)
    afp[nt] = *(const f16x8*)(abase + nt*16*NH);
  const int jbase = wj*64;
  for (int kk = 0; kk < 16; ++kk) {
    f16x8 af[4];
    #pragma unroll
    for (int nt = 0; nt < 4; ++nt) af[nt] = afp[nt];
    if (kk < 15) {
      #pragma unroll
      for (int nt = 0; nt < 4; ++nt)
        afp[nt] = *(const f16x8*)(abase + nt*16*NH + (kk+1)*32);
    }
    const char* tb = ldsb + (kk >> 1)*16384;
    const int kb = (kk & 1)*64 + lg*16;
    f16x8 bf[4];
    #pragma unroll
    for (int jt = 0; jt < 4; ++jt) {
      const int j = jbase + jt*16 + lr;
      bf[jt] = *(const f16x8*)(tb + ((j*128 + kb) ^ ((j & 7) << 4)));
    }
    __builtin_amdgcn_s_setprio(1);
    #pragma unroll
    for (int nt = 0; nt < 4; ++nt)
      #pragma unroll
      for (int jt = 0; jt < 4; ++jt)
        acc[nt][jt] = __builtin_amdgcn_mfma_f32_16x16x32_f16(af[nt], bf[jt], acc[nt][jt], 0, 0, 0);
    __builtin_amdgcn_s_setprio(0);
  }
}

__global__ __launch_bounds__(1024, 2) void edge_fused(
    const _Float16* __restrict__ u16, const _Float16* __restrict__ v16,
    const _Float16* __restrict__ w2h, const _Float16* __restrict__ w3h,
    const float* __restrict__ e2b, const float* __restrict__ e3b,
    const float* __restrict__ maskp, const float* __restrict__ cntp,
    const float* __restrict__ lng, const float* __restrict__ lnb,
    _Float16* __restrict__ nodein) {
  __shared__ __align__(16) char lds[131072];
  __shared__ float em_s[64];
  __shared__ float red_s[2][16];
  __shared__ float stat_s[2][2];

  const int t = threadIdx.x;
  const int bi0 = blockIdx.x * 2;      // two consecutive (b,i), same b
  const int b = bi0 >> 6;
  const int w = t >> 6, l = t & 63, lr = l & 15, lg = l >> 4;
  const int wj = w & 1;                // j-half = group
  const int wcol = (w >> 1) * 64;      // 64-col group

  if (t < 64) em_s[t] = maskp[(size_t)b*64 + t];

  // ---- build H1: row r (0..127): group r>>6, relu(u_{bi0+(r>>6)} + v_{r&63})
  {
    const int jrow = t >> 3;          // 0..127, one row per 8 threads
    const int kc = t & 7;             // k-tile 0..7 (64 elems)
    const _Float16* vrow = v16 + ((size_t)(b*64 + (jrow & 63)))*NH + kc*64;
    const _Float16* up   = u16 + (size_t)(bi0 + (jrow >> 6))*NH + kc*64;
    char* tbase = lds + kc*16384;
    #pragma unroll
    for (int e8 = 0; e8 < 8; ++e8) {
      f16x8 vv = *(const f16x8*)(vrow + e8*8);
      f16x8 uu = *(const f16x8*)(up + e8*8);
      f16x8 hv;
      #pragma unroll
      for (int e = 0; e < 8; ++e) {
        _Float16 x = uu[e] + vv[e];
        hv[e] = x > (_Float16)0 ? x : (_Float16)0;
      }
      *(f16x8*)(tbase + ((jrow*128 + e8*16) ^ ((jrow & 7) << 4))) = hv;
    }
  }
  __syncthreads();

  f32x4 acc[4][4];   // [nt][jt]; n = wcol+nt*16+lg*4+r, j = wj*64+jt*16+lr

  // ---- layer 2
  mlp_layer(lds, w2h, e2b, wcol, wj, lr, lg, acc);
  __syncthreads();   // all waves done reading H1

  // ---- H2 = relu(acc): f16x4 stores, n-channel = "k" dim of layer 3
  {
    char* tb = lds + (w >> 1)*16384;   // tile = wcol>>6
    const int nloc = (wcol & 63);      // 0 (wcol multiple of 64)
    #pragma unroll
    for (int jt = 0; jt < 4; ++jt) {
      const int j = wj*64 + jt*16 + lr;
      #pragma unroll
      for (int nt = 0; nt < 4; ++nt) {
        f16x4 hv;
        #pragma unroll
        for (int r = 0; r < 4; ++r)
          hv[r] = (_Float16)fmaxf(acc[nt][jt][r], 0.0f);
        const int bc = (nloc + nt*16 + lg*4)*2;
        *(f16x4*)(tb + ((j*128 + bc) ^ ((j & 7) << 4))) = hv;
      }
    }
  }
  __syncthreads();   // H2 complete

  // ---- layer 3
  mlp_layer(lds, w3h, e3b, wcol, wj, lr, lg, acc);

  // ---- masked j-sum (relu fused); wave's j-range = group wj
  float csum[4][4];   // [nt][r]
  #pragma unroll
  for (int nt = 0; nt < 4; ++nt)
    #pragma unroll
    for (int r = 0; r < 4; ++r) csum[nt][r] = 0.0f;
  #pragma unroll
  for (int jt = 0; jt < 4; ++jt) {
    float em = em_s[jt*16 + lr];
    #pragma unroll
    for (int nt = 0; nt < 4; ++nt)
      #pragma unroll
      for (int r = 0; r < 4; ++r)
        csum[nt][r] += em * fmaxf(acc[nt][jt][r], 0.0f);
  }
  #pragma unroll
  for (int nt = 0; nt < 4; ++nt)
    #pragma unroll
    for (int r = 0; r < 4; ++r) {
      csum[nt][r] += __shfl_xor(csum[nt][r], 1);
      csum[nt][r] += __shfl_xor(csum[nt][r], 2);
      csum[nt][r] += __shfl_xor(csum[nt][r], 4);
      csum[nt][r] += __shfl_xor(csum[nt][r], 8);
    }
  float cnt = cntp[b];
  __syncthreads();   // all H2 reads done; reuse lds head as agg[2][512]
  float* aggs = (float*)lds;
  if (lr == 0) {
    float sc = em_s[(bi0 & 63) + wj] / cnt;
    #pragma unroll
    for (int nt = 0; nt < 4; ++nt) {
      float4 av;
      av.x = csum[nt][0] * sc; av.y = csum[nt][1] * sc;
      av.z = csum[nt][2] * sc; av.w = csum[nt][3] * sc;
      *(float4*)(aggs + wj*512 + wcol + nt*16 + lg*4) = av;
    }
  }
  __syncthreads();

  // ---- LayerNorm: threads [0,512) -> group 0, [512,1024) -> group 1
  {
    const int g = t >> 9;
    const int t5 = t & 511;
    const int w5 = t5 >> 6;
    float a = aggs[g*512 + t5];
    float s1 = a, s2 = a * a;
    #pragma unroll
    for (int off = 1; off < 64; off <<= 1) {
      s1 += __shfl_xor(s1, off);
      s2 += __shfl_xor(s2, off);
    }
    if (l == 0) { red_s[g][w5] = s1; red_s[g][8 + w5] = s2; }
    __syncthreads();
    if (t5 == 0) {
      float S1 = 0.f, S2 = 0.f;
      #pragma unroll
      for (int q = 0; q < 8; ++q) { S1 += red_s[g][q]; S2 += red_s[g][8 + q]; }
      float mean = S1 * (1.0f/512.0f);
      float var = S2 * (1.0f/512.0f) - mean * mean;
      stat_s[g][0] = mean;
      stat_s[g][1] = rsqrtf(var + 1e-5f);
    }
    __syncthreads();
    float nrm = (a - stat_s[g][0]) * stat_s[g][1] * lng[t5] + lnb[t5];
    nodein[(size_t)(bi0 + g)*NKP + 4 + t5] = (_Float16)nrm;
  }
}

// ---------------------------------------------------------------- node ----

template <int RELU16>
__global__ __launch_bounds__(256) void node_gemm(
    const _Float16* __restrict__ A, const _Float16* __restrict__ Bw,
    const float* __restrict__ bias, void* __restrict__ outp,
    int Ka, int ldo) {
  const int t = threadIdx.x;
  const int w = t >> 6, l = t & 63, lr = l & 15, lg = l >> 4;
  const int m0 = blockIdx.x * 64;
  const int col = blockIdx.y * 64 + w*16 + lr;
  f32x4 acc[4];
  float bz = bias[col];
  #pragma unroll
  for (int mt = 0; mt < 4; ++mt) {
    acc[mt][0] = bz; acc[mt][1] = bz; acc[mt][2] = bz; acc[mt][3] = bz;
  }
  const _Float16* bptr = Bw + (size_t)col*Ka + lg*8;
  const _Float16* aptr = A + (size_t)(m0 + lr)*Ka + lg*8;
  const int nkk = Ka >> 5;
  for (int kk = 0; kk < nkk; ++kk) {
    f16x8 bf = *(const f16x8*)(bptr + kk*32);
    #pragma unroll
    for (int mt = 0; mt < 4; ++mt) {
      f16x8 af = *(const f16x8*)(aptr + ((size_t)mt*16)*Ka + kk*32);
      acc[mt] = __builtin_amdgcn_mfma_f32_16x16x32_f16(af, bf, acc[mt], 0, 0, 0);
    }
  }
  #pragma unroll
  for (int mt = 0; mt < 4; ++mt)
    #pragma unroll
    for (int r = 0; r < 4; ++r) {
      int row = m0 + mt*16 + lg*4 + r;
      float vv = acc[mt][r];
      if (RELU16)
        ((_Float16*)outp)[(size_t)row*ldo + col] = (_Float16)fmaxf(vv, 0.f);
      else
        ((float*)outp)[(size_t)row*ldo + col] = vv;
    }
}

// ----------------------------------------------------------- pool/heads ----

__global__ __launch_bounds__(256) void pool_kernel(
    const float* __restrict__ nodeout, const float* __restrict__ maskp,
    const float* __restrict__ cntp, float* __restrict__ xfeat) {
  const int b = blockIdx.x;
  const int c = threadIdx.x;  // 256
  float sum = 0.f, mx = -1e9f;
  for (int i = 0; i < 64; ++i) {
    float m = maskp[b*64 + i];
    float v = nodeout[((size_t)(b*64 + i))*256 + c];
    sum += m * v;
    mx = fmaxf(mx, (m != 0.f) ? v : -1e9f);
  }
  xfeat[b*1024 + 512 + c] = sum / cntp[b];
  xfeat[b*1024 + 768 + c] = mx;
}

// heads stage 1: partial dots over a 256-wide K slice.
__global__ __launch_bounds__(256) void heads_g1(
    const float* __restrict__ xfeat,
    const float* __restrict__ mu1w, const float* __restrict__ s1w,
    float* __restrict__ part) {
  __shared__ __align__(16) float xs[256];
  const int b = blockIdx.x, h = blockIdx.y, ks = blockIdx.z;
  const int t = threadIdx.x;
  xs[t] = xfeat[b*1024 + ks*256 + t];
  __syncthreads();
  const float* wr = (h ? s1w : mu1w) + (size_t)t*1024 + ks*256;
  float a = 0.f;
  #pragma unroll 8
  for (int k = 0; k < 256; k += 4) {
    float4 ww = *(const float4*)(wr + k);
    float4 xx = *(const float4*)(xs + k);
    a += ww.x*xx.x + ww.y*xx.y + ww.z*xx.z + ww.w*xx.w;
  }
  part[(((size_t)(b*2 + h))*256 + t)*4 + ks] = a;
}

// heads stage 2+3.
__global__ __launch_bounds__(256) void heads_g23(
    const float* __restrict__ part,
    const float* __restrict__ mu1b, const float* __restrict__ s1b,
    const float* __restrict__ mu2w, const float* __restrict__ mu2b,
    const float* __restrict__ s2w, const float* __restrict__ s2b,
    const float* __restrict__ mu3w, const float* __restrict__ mu3b,
    const float* __restrict__ s3w, const float* __restrict__ s3b,
    float* __restrict__ outp) {
  __shared__ __align__(16) float h1s[256];
  __shared__ __align__(16) float h2s[128];
  const int b = blockIdx.x, h = blockIdx.y;
  const int t = threadIdx.x;
  {
    float4 pp = *(const float4*)(part + (((size_t)(b*2 + h))*256 + t)*4);
    float a = pp.x + pp.y + pp.z + pp.w + (h ? s1b : mu1b)[t];
    h1s[t] = fmaxf(a, 0.f);
  }
  __syncthreads();
  {
    const int o = t >> 1, half = t & 1;
    const float* wr = (h ? s2w : mu2w) + (size_t)o*256 + half*128;
    const float* hp = h1s + half*128;
    float a = 0.f;
    #pragma unroll 8
    for (int k = 0; k < 128; k += 4) {
      float4 ww = *(const float4*)(wr + k);
      float4 hh = *(const float4*)(hp + k);
      a += ww.x*hh.x + ww.y*hh.y + ww.z*hh.z + ww.w*hh.w;
    }
    a += __shfl_xor(a, 1);
    if (half == 0) h2s[o] = fmaxf(a + (h ? s2b : mu2b)[o], 0.f);
  }
  __syncthreads();
  if (t < 64) {
    const int o = t >> 5, lane = t & 31;
    const float* wr = (h ? s3w : mu3w) + o*128 + lane*4;
    const float* hp = h2s + lane*4;
    float4 ww = *(const float4*)wr;
    float4 hh = *(const float4*)hp;
    float a = ww.x*hh.x + ww.y*hh.y + ww.z*hh.z + ww.w*hh.w;
    #pragma unroll
    for (int off = 1; off < 32; off <<= 1) a += __shfl_xor(a, off);
    if (lane == 0) {
      a += (h ? s3b : mu3b)[o];
      if (h == 0) {
        outp[b*2 + o] = a;
      } else {
        float spv = (a > 0.f) ? (a + log1pf(expf(-a))) : log1pf(expf(a));
        outp[64 + b*2 + o] = fminf(fmaxf(spv + 0.001f, 0.1f), 2.0f);
      }
    }
  }
}

// --------------------------------------------------------------- launch ----

extern "C" void kernel_launch(void* const* d_in, const int* in_sizes, int n_in,
                              void* d_out, int out_size, void* d_ws, size_t ws_size,
                              hipStream_t stream) {
  const float* state  = (const float*)d_in[0];
  const float* obs    = (const float*)d_in[1];
  const float* layerw = (const float*)d_in[2];
  const float* layerb = (const float*)d_in[3];
  const float* e1w    = (const float*)d_in[4];
  const float* e1b    = (const float*)d_in[5];
  const float* e2w    = (const float*)d_in[6];
  const float* e2b    = (const float*)d_in[7];
  const float* e3w    = (const float*)d_in[8];
  const float* e3b    = (const float*)d_in[9];
  const float* lng    = (const float*)d_in[10];
  const float* lnb    = (const float*)d_in[11];
  const float* n1w    = (const float*)d_in[12];
  const float* n1b    = (const float*)d_in[13];
  const float* n2w    = (const float*)d_in[14];
  const float* n2b    = (const float*)d_in[15];
  const float* mu1w   = (const float*)d_in[16];
  const float* mu1b   = (const float*)d_in[17];
  const float* mu2w   = (const float*)d_in[18];
  const float* mu2b   = (const float*)d_in[19];
  const float* mu3w   = (const float*)d_in[20];
  const float* mu3b   = (const float*)d_in[21];
  const float* s1w    = (const float*)d_in[22];
  const float* s1b    = (const float*)d_in[23];
  const float* s2w    = (const float*)d_in[24];
  const float* s2b    = (const float*)d_in[25];
  const float* s3w    = (const float*)d_in[26];
  const float* s3b    = (const float*)d_in[27];
  float* outp = (float*)d_out;

  char* p = (char*)d_ws;
  auto alloc = [&](size_t bytes) {
    char* r = p;
    p += (bytes + 255) & ~(size_t)255;
    return r;
  };
  float*    o       = (float*)alloc((size_t)2048*4*4);
  float*    maskp   = (float*)alloc((size_t)2048*4);
  float*    cntp    = (float*)alloc((size_t)32*4);
  _Float16* u16     = (_Float16*)alloc((size_t)2048*512*2);
  _Float16* v16     = (_Float16*)alloc((size_t)2048*512*2);
  _Float16* w2h     = (_Float16*)alloc((size_t)512*512*2);
  _Float16* w3h     = (_Float16*)alloc((size_t)512*512*2);
  _Float16* nodein  = (_Float16*)alloc((size_t)2048*544*2);
  _Float16* n1wh    = (_Float16*)alloc((size_t)512*544*2);
  _Float16* n2wh    = (_Float16*)alloc((size_t)256*512*2);
  _Float16* nodeh   = (_Float16*)alloc((size_t)2048*512*2);
  float*    nodeout = (float*)alloc((size_t)2048*256*4);
  float*    xfeat   = (float*)alloc((size_t)32*1024*4);
  float*    hpart   = (float*)alloc((size_t)32*2*256*4*4);

  prep_obs_kernel<<<32, 64, 0, stream>>>(obs, state, o, maskp, cntp, nodein);
  prep_uv16<<<2048, 512, 0, stream>>>(o, e1w, e1b, u16, v16);
  prep_w16_kernel<<<3648, 256, 0, stream>>>(e2w, e3w, n2w, n1w, w2h, w3h, n2wh, n1wh);
  prep_stfeat_kernel<<<32, 512, 0, stream>>>(state, layerw, layerb, xfeat);

  edge_fused<<<1024, 1024, 0, stream>>>(u16, v16, w2h, w3h, e2b, e3b,
                                        maskp, cntp, lng, lnb, nodein);

  node_gemm<1><<<dim3(32, 8), 256, 0, stream>>>(nodein, n1wh, n1b, (void*)nodeh, 544, 512);
  node_gemm<0><<<dim3(32, 4), 256, 0, stream>>>(nodeh, n2wh, n2b, (void*)nodeout, 512, 256);
  pool_kernel<<<32, 256, 0, stream>>>(nodeout, maskp, cntp, xfeat);
  heads_g1<<<dim3(32, 2, 4), 256, 0, stream>>>(xfeat, mu1w, s1w, hpart);
  heads_g23<<<dim3(32, 2), 256, 0, stream>>>(hpart, mu1b, s1b, mu2w, mu2b,
                                             s2w, s2b, mu3w, mu3b, s3w, s3b, outp);
}

// Round 10
// 240.094 us; speedup vs baseline: 1.7554x; 1.7554x over previous
//
#include <hip/hip_runtime.h>
#include <hip/hip_fp16.h>

typedef _Float16 f16x8 __attribute__((ext_vector_type(8)));
typedef _Float16 f16x4 __attribute__((ext_vector_type(4)));
typedef float f32x4 __attribute__((ext_vector_type(4)));

#define NB 32
#define NK 64
#define ND 4
#define NH 512
#define NKP 544   // node-input K (520) padded to 17*32

// ---------------------------------------------------------------- prep ----

__global__ void prep_obs_kernel(const float* __restrict__ obs,
                                const float* __restrict__ state,
                                float* __restrict__ o,
                                float* __restrict__ maskp,
                                float* __restrict__ cntp,
                                _Float16* __restrict__ nodein) {
  const int b = blockIdx.x;
  const int j = threadIdx.x;  // 64
  float o0 = obs[(b*4 + 0)*64 + j];
  float o1 = obs[(b*4 + 1)*64 + j];
  float o2 = obs[(b*4 + 2)*64 + j];
  float o3 = obs[(b*4 + 3)*64 + j];
  size_t bi = (size_t)b*64 + j;
  float* orow = o + bi*4;
  orow[0] = o0; orow[1] = o1; orow[2] = o2; orow[3] = o3;
  float s = fabsf(o0) + fabsf(o1) + fabsf(o2) + fabsf(o3);
  float m = (s != 0.0f) ? 1.0f : 0.0f;
  maskp[bi] = m;
  float c = m;
  #pragma unroll
  for (int off = 1; off < 64; off <<= 1) c += __shfl_xor(c, off);
  if (j == 0) cntp[b] = fmaxf(c, 1e-6f);
  _Float16* nrow = nodein + bi*NKP;
  nrow[0] = (_Float16)o0; nrow[1] = (_Float16)o1;
  nrow[2] = (_Float16)o2; nrow[3] = (_Float16)o3;
  nrow[516] = (_Float16)state[b*4 + 0];
  nrow[517] = (_Float16)state[b*4 + 1];
  nrow[518] = (_Float16)state[b*4 + 2];
  nrow[519] = (_Float16)state[b*4 + 3];
  for (int k2 = 520; k2 < 544; ++k2) nrow[k2] = (_Float16)0.0f;
}

// u16[bi][c] = W1[:, :4]·o_bi + b1  (f16);  v16[bi][c] = W1[:, 4:]·o_bi (f16)
__global__ void prep_uv16(const float* __restrict__ o,
                          const float* __restrict__ e1w,
                          const float* __restrict__ e1b,
                          _Float16* __restrict__ u16,
                          _Float16* __restrict__ v16) {
  const int bi = blockIdx.x;     // 2048
  const int c = threadIdx.x;     // 512
  const float* orow = o + (size_t)bi*4;
  float o0 = orow[0], o1 = orow[1], o2 = orow[2], o3 = orow[3];
  const float* wr = e1w + c*8;
  float u = wr[0]*o0 + wr[1]*o1 + wr[2]*o2 + wr[3]*o3 + e1b[c];
  float v = wr[4]*o0 + wr[5]*o1 + wr[6]*o2 + wr[7]*o3;
  u16[(size_t)bi*NH + c] = (_Float16)u;
  v16[(size_t)bi*NH + c] = (_Float16)v;
}

__global__ void prep_w16_kernel(const float* __restrict__ e2w,
                                const float* __restrict__ e3w,
                                const float* __restrict__ n2w,
                                const float* __restrict__ n1w,
                                _Float16* __restrict__ w2h,
                                _Float16* __restrict__ w3h,
                                _Float16* __restrict__ n2wh,
                                _Float16* __restrict__ n1wh) {
  int idx = blockIdx.x * blockDim.x + threadIdx.x;
  const int A = 512*512, Bc = 512*512, C = 256*512, Dn = 512*544;
  if (idx < A) {
    w2h[idx] = (_Float16)e2w[idx];
  } else if (idx < A + Bc) {
    int q = idx - A; w3h[q] = (_Float16)e3w[q];
  } else if (idx < A + Bc + C) {
    int q = idx - A - Bc; n2wh[q] = (_Float16)n2w[q];
  } else if (idx < A + Bc + C + Dn) {
    int q = idx - A - Bc - C;
    int n = q / 544, k = q % 544;
    n1wh[q] = (k < 520) ? (_Float16)n1w[n*520 + k] : (_Float16)0.0f;
  }
}

__global__ void prep_stfeat_kernel(const float* __restrict__ state,
                                   const float* __restrict__ lw,
                                   const float* __restrict__ lb,
                                   float* __restrict__ xfeat) {
  const int b = blockIdx.x, c = threadIdx.x;  // 512
  const float* s = state + b*4;
  const float* wr = lw + c*4;
  float hv = wr[0]*s[0] + wr[1]*s[1] + wr[2]*s[2] + wr[3]*s[3] + lb[c];
  xfeat[b*1024 + c] = fmaxf(hv, 0.0f);
}

// ----------------------------------------------------- edge (fused MLP) ----
// R4 structure (best measured: edge 184 us) with two changes:
//  1. __launch_bounds__(512, 1): arg2 is min BLOCKS/CU on this toolchain
//     (measured R4/R7/R9: VGPR cap = 512/(arg2*waves_per_block/4)).
//     (512,1) -> 256-VGPR budget; occupancy unchanged (128 KB LDS already
//     limits to 1 WG/CU).
//  2. Batched af[8] LDS reads per k-step: 8 independent ds_read_b128 in
//     flight instead of R4's serialized read->4xMFMA chain (the measured
//     33% MfmaUtil matched that serialization model).
// One WG = 128 rows (2 (b,i) x 64 j), 8 waves, wave = all 128 j x 64 n.
// A-frag = H rows (LDS), B-frag = W rows (global/L2). D: row=j, col=n.
// H: [128][512] f16, byte(row,k) = (row*1024 + k*2) ^ ((row&7)<<4).

__device__ __forceinline__ void mlp_layer(const char* hb,
                                          const _Float16* __restrict__ wbase0,
                                          const float* __restrict__ biasp,
                                          int wcol, int lr, int lg,
                                          f32x4 acc[8][4]) {
  #pragma unroll
  for (int nt = 0; nt < 4; ++nt) {
    float bz = biasp[wcol + nt*16 + lr];
    #pragma unroll
    for (int mt = 0; mt < 8; ++mt) {
      acc[mt][nt][0] = bz; acc[mt][nt][1] = bz;
      acc[mt][nt][2] = bz; acc[mt][nt][3] = bz;
    }
  }
  const _Float16* bbase = wbase0 + (size_t)(wcol + lr)*NH + lg*8;
  f16x8 bfp[4];
  #pragma unroll
  for (int nt = 0; nt < 4; ++nt)
    bfp[nt] = *(const f16x8*)(bbase + nt*16*NH);
  for (int kk = 0; kk < 16; ++kk) {
    f16x8 bf[4];
    #pragma unroll
    for (int nt = 0; nt < 4; ++nt) bf[nt] = bfp[nt];
    if (kk < 15) {
      #pragma unroll
      for (int nt = 0; nt < 4; ++nt)
        bfp[nt] = *(const f16x8*)(bbase + nt*16*NH + (kk+1)*32);
    }
    // batched LDS reads: 8 independent ds_read_b128 in flight
    f16x8 af[8];
    #pragma unroll
    for (int mt = 0; mt < 8; ++mt) {
      const int row = mt*16 + lr;
      af[mt] = *(const f16x8*)(hb + ((row*1024 + kk*64 + lg*16) ^ ((row & 7) << 4)));
    }
    #pragma unroll
    for (int mt = 0; mt < 8; ++mt)
      #pragma unroll
      for (int nt = 0; nt < 4; ++nt)
        acc[mt][nt] = __builtin_amdgcn_mfma_f32_16x16x32_f16(af[mt], bf[nt], acc[mt][nt], 0, 0, 0);
  }
}

__global__ __launch_bounds__(512, 1) void edge_fused(
    const _Float16* __restrict__ u16, const _Float16* __restrict__ v16,
    const _Float16* __restrict__ w2h, const _Float16* __restrict__ w3h,
    const float* __restrict__ e2b, const float* __restrict__ e3b,
    const float* __restrict__ maskp, const float* __restrict__ cntp,
    const float* __restrict__ lng, const float* __restrict__ lnb,
    _Float16* __restrict__ nodein) {
  __shared__ __align__(16) char lds[131072];
  __shared__ float em_s[64];
  __shared__ float red_s[16];
  __shared__ float stat_s[2];

  const int t = threadIdx.x;
  const int bi0 = blockIdx.x * 2;      // two consecutive (b,i), same b
  const int b = bi0 >> 6;
  const int w = t >> 6, l = t & 63, lr = l & 15, lg = l >> 4;
  const int wcol = w * 64;

  if (t < 64) em_s[t] = maskp[(size_t)b*64 + t];

  // ---- build H1: rows 0-63 = relu(u0+v_j), rows 64-127 = relu(u1+v_j)
  {
    const int jrow = t >> 3;    // j 0..63
    const int kc = t & 7;       // 64-elem k chunk
    const _Float16* vrow = v16 + ((size_t)(b*64 + jrow))*NH + kc*64;
    const _Float16* u0p  = u16 + (size_t)bi0*NH + kc*64;
    const _Float16* u1p  = u16 + (size_t)(bi0 + 1)*NH + kc*64;
    #pragma unroll
    for (int e8 = 0; e8 < 8; ++e8) {
      f16x8 vv = *(const f16x8*)(vrow + e8*8);
      f16x8 u0 = *(const f16x8*)(u0p + e8*8);
      f16x8 u1 = *(const f16x8*)(u1p + e8*8);
      f16x8 h0, h1;
      #pragma unroll
      for (int e = 0; e < 8; ++e) {
        _Float16 x0 = u0[e] + vv[e];
        _Float16 x1 = u1[e] + vv[e];
        h0[e] = x0 > (_Float16)0 ? x0 : (_Float16)0;
        h1[e] = x1 > (_Float16)0 ? x1 : (_Float16)0;
      }
      const int bc = (kc*64 + e8*8)*2;
      const int r1 = 64 + jrow;
      *(f16x8*)(lds + ((jrow*1024 + bc) ^ ((jrow & 7) << 4))) = h0;
      *(f16x8*)(lds + ((r1*1024 + bc) ^ ((r1 & 7) << 4))) = h1;
    }
  }
  __syncthreads();

  f32x4 acc[8][4];   // [mt][nt]; j-row = mt*16 + lg*4 + r, n = wcol+nt*16+lr

  // ---- layer 2: acc = H1 @ W2^T + b2
  mlp_layer(lds, w2h, e2b, wcol, lr, lg, acc);
  __syncthreads();   // all waves done reading H1

  // ---- H2 = relu(acc) overwrites the same LDS buffer (same layout)
  #pragma unroll
  for (int mt = 0; mt < 8; ++mt)
    #pragma unroll
    for (int nt = 0; nt < 4; ++nt)
      #pragma unroll
      for (int r = 0; r < 4; ++r) {
        int row = mt*16 + lg*4 + r;
        int cc = wcol + nt*16 + lr;
        *(_Float16*)(lds + ((row*1024 + cc*2) ^ ((row & 7) << 4))) =
            (_Float16)fmaxf(acc[mt][nt][r], 0.0f);
      }
  __syncthreads();   // H2 complete

  // ---- layer 3: acc = H2 @ W3^T + b3
  mlp_layer(lds, w3h, e3b, wcol, lr, lg, acc);

  // ---- relu + mask-weighted sum over j; rows 0-63 -> bi0, 64-127 -> bi0+1
  float csum[2][4] = {{0.f,0.f,0.f,0.f},{0.f,0.f,0.f,0.f}};
  #pragma unroll
  for (int mt = 0; mt < 8; ++mt) {
    const int g = mt >> 2;
    float em0 = em_s[(mt&3)*16 + lg*4 + 0];
    float em1 = em_s[(mt&3)*16 + lg*4 + 1];
    float em2 = em_s[(mt&3)*16 + lg*4 + 2];
    float em3 = em_s[(mt&3)*16 + lg*4 + 3];
    #pragma unroll
    for (int nt = 0; nt < 4; ++nt) {
      csum[g][nt] += em0 * fmaxf(acc[mt][nt][0], 0.f)
                   + em1 * fmaxf(acc[mt][nt][1], 0.f)
                   + em2 * fmaxf(acc[mt][nt][2], 0.f)
                   + em3 * fmaxf(acc[mt][nt][3], 0.f);
    }
  }
  #pragma unroll
  for (int g = 0; g < 2; ++g)
    #pragma unroll
    for (int nt = 0; nt < 4; ++nt) {
      csum[g][nt] += __shfl_xor(csum[g][nt], 16);
      csum[g][nt] += __shfl_xor(csum[g][nt], 32);
    }
  float cnt = cntp[b];
  __syncthreads();   // done with H2 reads; reuse lds as agg[2][512]
  float* aggs = (float*)lds;
  if (lg == 0) {
    #pragma unroll
    for (int g = 0; g < 2; ++g) {
      int big = bi0 + g;
      float sc = em_s[big & 63] / cnt;
      #pragma unroll
      for (int nt = 0; nt < 4; ++nt)
        aggs[g*512 + wcol + nt*16 + lr] = csum[g][nt] * sc;
    }
  }
  __syncthreads();

  // ---- LayerNorm (both rows) + nodein write
  for (int g = 0; g < 2; ++g) {
    float a = aggs[g*512 + t];
    float s1 = a, s2 = a * a;
    #pragma unroll
    for (int off = 1; off < 64; off <<= 1) {
      s1 += __shfl_xor(s1, off);
      s2 += __shfl_xor(s2, off);
    }
    if (l == 0) { red_s[w] = s1; red_s[8 + w] = s2; }
    __syncthreads();
    if (t == 0) {
      float S1 = 0.f, S2 = 0.f;
      #pragma unroll
      for (int q = 0; q < 8; ++q) { S1 += red_s[q]; S2 += red_s[8 + q]; }
      float mean = S1 * (1.0f/512.0f);
      float var = S2 * (1.0f/512.0f) - mean * mean;
      stat_s[0] = mean;
      stat_s[1] = rsqrtf(var + 1e-5f);
    }
    __syncthreads();
    float nrm = (a - stat_s[0]) * stat_s[1] * lng[t] + lnb[t];
    nodein[(size_t)(bi0 + g)*NKP + 4 + t] = (_Float16)nrm;
    __syncthreads();   // protect red_s/stat_s before next g
  }
}

// ---------------------------------------------------------------- node ----

template <int RELU16>
__global__ __launch_bounds__(256) void node_gemm(
    const _Float16* __restrict__ A, const _Float16* __restrict__ Bw,
    const float* __restrict__ bias, void* __restrict__ outp,
    int Ka, int ldo) {
  const int t = threadIdx.x;
  const int w = t >> 6, l = t & 63, lr = l & 15, lg = l >> 4;
  const int m0 = blockIdx.x * 64;
  const int col = blockIdx.y * 64 + w*16 + lr;
  f32x4 acc[4];
  float bz = bias[col];
  #pragma unroll
  for (int mt = 0; mt < 4; ++mt) {
    acc[mt][0] = bz; acc[mt][1] = bz; acc[mt][2] = bz; acc[mt][3] = bz;
  }
  const _Float16* bptr = Bw + (size_t)col*Ka + lg*8;
  const _Float16* aptr = A + (size_t)(m0 + lr)*Ka + lg*8;
  const int nkk = Ka >> 5;
  for (int kk = 0; kk < nkk; ++kk) {
    f16x8 bf = *(const f16x8*)(bptr + kk*32);
    #pragma unroll
    for (int mt = 0; mt < 4; ++mt) {
      f16x8 af = *(const f16x8*)(aptr + ((size_t)mt*16)*Ka + kk*32);
      acc[mt] = __builtin_amdgcn_mfma_f32_16x16x32_f16(af, bf, acc[mt], 0, 0, 0);
    }
  }
  #pragma unroll
  for (int mt = 0; mt < 4; ++mt)
    #pragma unroll
    for (int r = 0; r < 4; ++r) {
      int row = m0 + mt*16 + lg*4 + r;
      float vv = acc[mt][r];
      if (RELU16)
        ((_Float16*)outp)[(size_t)row*ldo + col] = (_Float16)fmaxf(vv, 0.f);
      else
        ((float*)outp)[(size_t)row*ldo + col] = vv;
    }
}

// ----------------------------------------------------------- pool/heads ----

__global__ __launch_bounds__(256) void pool_kernel(
    const float* __restrict__ nodeout, const float* __restrict__ maskp,
    const float* __restrict__ cntp, float* __restrict__ xfeat) {
  const int b = blockIdx.x;
  const int c = threadIdx.x;  // 256
  float sum = 0.f, mx = -1e9f;
  for (int i = 0; i < 64; ++i) {
    float m = maskp[b*64 + i];
    float v = nodeout[((size_t)(b*64 + i))*256 + c];
    sum += m * v;
    mx = fmaxf(mx, (m != 0.f) ? v : -1e9f);
  }
  xfeat[b*1024 + 512 + c] = sum / cntp[b];
  xfeat[b*1024 + 768 + c] = mx;
}

// heads stage 1: partial dots over a 256-wide K slice.
__global__ __launch_bounds__(256) void heads_g1(
    const float* __restrict__ xfeat,
    const float* __restrict__ mu1w, const float* __restrict__ s1w,
    float* __restrict__ part) {
  __shared__ __align__(16) float xs[256];
  const int b = blockIdx.x, h = blockIdx.y, ks = blockIdx.z;
  const int t = threadIdx.x;
  xs[t] = xfeat[b*1024 + ks*256 + t];
  __syncthreads();
  const float* wr = (h ? s1w : mu1w) + (size_t)t*1024 + ks*256;
  float a = 0.f;
  #pragma unroll 8
  for (int k = 0; k < 256; k += 4) {
    float4 ww = *(const float4*)(wr + k);
    float4 xx = *(const float4*)(xs + k);
    a += ww.x*xx.x + ww.y*xx.y + ww.z*xx.z + ww.w*xx.w;
  }
  part[(((size_t)(b*2 + h))*256 + t)*4 + ks] = a;
}

// heads stage 2+3.
__global__ __launch_bounds__(256) void heads_g23(
    const float* __restrict__ part,
    const float* __restrict__ mu1b, const float* __restrict__ s1b,
    const float* __restrict__ mu2w, const float* __restrict__ mu2b,
    const float* __restrict__ s2w, const float* __restrict__ s2b,
    const float* __restrict__ mu3w, const float* __restrict__ mu3b,
    const float* __restrict__ s3w, const float* __restrict__ s3b,
    float* __restrict__ outp) {
  __shared__ __align__(16) float h1s[256];
  __shared__ __align__(16) float h2s[128];
  const int b = blockIdx.x, h = blockIdx.y;
  const int t = threadIdx.x;
  {
    float4 pp = *(const float4*)(part + (((size_t)(b*2 + h))*256 + t)*4);
    float a = pp.x + pp.y + pp.z + pp.w + (h ? s1b : mu1b)[t];
    h1s[t] = fmaxf(a, 0.f);
  }
  __syncthreads();
  {
    const int o = t >> 1, half = t & 1;
    const float* wr = (h ? s2w : mu2w) + (size_t)o*256 + half*128;
    const float* hp = h1s + half*128;
    float a = 0.f;
    #pragma unroll 8
    for (int k = 0; k < 128; k += 4) {
      float4 ww = *(const float4*)(wr + k);
      float4 hh = *(const float4*)(hp + k);
      a += ww.x*hh.x + ww.y*hh.y + ww.z*hh.z + ww.w*hh.w;
    }
    a += __shfl_xor(a, 1);
    if (half == 0) h2s[o] = fmaxf(a + (h ? s2b : mu2b)[o], 0.f);
  }
  __syncthreads();
  if (t < 64) {
    const int o = t >> 5, lane = t & 31;
    const float* wr = (h ? s3w : mu3w) + o*128 + lane*4;
    const float* hp = h2s + lane*4;
    float4 ww = *(const float4*)wr;
    float4 hh = *(const float4*)hp;
    float a = ww.x*hh.x + ww.y*hh.y + ww.z*hh.z + ww.w*hh.w;
    #pragma unroll
    for (int off = 1; off < 32; off <<= 1) a += __shfl_xor(a, off);
    if (lane == 0) {
      a += (h ? s3b : mu3b)[o];
      if (h == 0) {
        outp[b*2 + o] = a;
      } else {
        float spv = (a > 0.f) ? (a + log1pf(expf(-a))) : log1pf(expf(a));
        outp[64 + b*2 + o] = fminf(fmaxf(spv + 0.001f, 0.1f), 2.0f);
      }
    }
  }
}

// --------------------------------------------------------------- launch ----

extern "C" void kernel_launch(void* const* d_in, const int* in_sizes, int n_in,
                              void* d_out, int out_size, void* d_ws, size_t ws_size,
                              hipStream_t stream) {
  const float* state  = (const float*)d_in[0];
  const float* obs    = (const float*)d_in[1];
  const float* layerw = (const float*)d_in[2];
  const float* layerb = (const float*)d_in[3];
  const float* e1w    = (const float*)d_in[4];
  const float* e1b    = (const float*)d_in[5];
  const float* e2w    = (const float*)d_in[6];
  const float* e2b    = (const float*)d_in[7];
  const float* e3w    = (const float*)d_in[8];
  const float* e3b    = (const float*)d_in[9];
  const float* lng    = (const float*)d_in[10];
  const float* lnb    = (const float*)d_in[11];
  const float* n1w    = (const float*)d_in[12];
  const float* n1b    = (const float*)d_in[13];
  const float* n2w    = (const float*)d_in[14];
  const float* n2b    = (const float*)d_in[15];
  const float* mu1w   = (const float*)d_in[16];
  const float* mu1b   = (const float*)d_in[17];
  const float* mu2w   = (const float*)d_in[18];
  const float* mu2b   = (const float*)d_in[19];
  const float* mu3w   = (const float*)d_in[20];
  const float* mu3b   = (const float*)d_in[21];
  const float* s1w    = (const float*)d_in[22];
  const float* s1b    = (const float*)d_in[23];
  const float* s2w    = (const float*)d_in[24];
  const float* s2b    = (const float*)d_in[25];
  const float* s3w    = (const float*)d_in[26];
  const float* s3b    = (const float*)d_in[27];
  float* outp = (float*)d_out;

  char* p = (char*)d_ws;
  auto alloc = [&](size_t bytes) {
    char* r = p;
    p += (bytes + 255) & ~(size_t)255;
    return r;
  };
  float*    o       = (float*)alloc((size_t)2048*4*4);
  float*    maskp   = (float*)alloc((size_t)2048*4);
  float*    cntp    = (float*)alloc((size_t)32*4);
  _Float16* u16     = (_Float16*)alloc((size_t)2048*512*2);
  _Float16* v16     = (_Float16*)alloc((size_t)2048*512*2);
  _Float16* w2h     = (_Float16*)alloc((size_t)512*512*2);
  _Float16* w3h     = (_Float16*)alloc((size_t)512*512*2);
  _Float16* nodein  = (_Float16*)alloc((size_t)2048*544*2);
  _Float16* n1wh    = (_Float16*)alloc((size_t)512*544*2);
  _Float16* n2wh    = (_Float16*)alloc((size_t)256*512*2);
  _Float16* nodeh   = (_Float16*)alloc((size_t)2048*512*2);
  float*    nodeout = (float*)alloc((size_t)2048*256*4);
  float*    xfeat   = (float*)alloc((size_t)32*1024*4);
  float*    hpart   = (float*)alloc((size_t)32*2*256*4*4);

  prep_obs_kernel<<<32, 64, 0, stream>>>(obs, state, o, maskp, cntp, nodein);
  prep_uv16<<<2048, 512, 0, stream>>>(o, e1w, e1b, u16, v16);
  prep_w16_kernel<<<3648, 256, 0, stream>>>(e2w, e3w, n2w, n1w, w2h, w3h, n2wh, n1wh);
  prep_stfeat_kernel<<<32, 512, 0, stream>>>(state, layerw, layerb, xfeat);

  edge_fused<<<1024, 512, 0, stream>>>(u16, v16, w2h, w3h, e2b, e3b,
                                       maskp, cntp, lng, lnb, nodein);

  node_gemm<1><<<dim3(32, 8), 256, 0, stream>>>(nodein, n1wh, n1b, (void*)nodeh, 544, 512);
  node_gemm<0><<<dim3(32, 4), 256, 0, stream>>>(nodeh, n2wh, n2b, (void*)nodeout, 512, 256);
  pool_kernel<<<32, 256, 0, stream>>>(nodeout, maskp, cntp, xfeat);
  heads_g1<<<dim3(32, 2, 4), 256, 0, stream>>>(xfeat, mu1w, s1w, hpart);
  heads_g23<<<dim3(32, 2), 256, 0, stream>>>(hpart, mu1b, s1b, mu2w, mu2b,
                                             s2w, s2b, mu3w, mu3b, s3w, s3b, outp);
}

// Round 11
// 230.117 us; speedup vs baseline: 1.8315x; 1.0434x over previous
//
#include <hip/hip_runtime.h>
#include <hip/hip_fp16.h>

typedef _Float16 f16x8 __attribute__((ext_vector_type(8)));
typedef _Float16 f16x4 __attribute__((ext_vector_type(4)));
typedef float f32x4 __attribute__((ext_vector_type(4)));

#define NB 32
#define NK 64
#define ND 4
#define NH 512
#define NKP 544   // node-input K (520) padded to 17*32

// ---------------------------------------------------------------- prep ----

__global__ void prep_obs_kernel(const float* __restrict__ obs,
                                const float* __restrict__ state,
                                float* __restrict__ o,
                                float* __restrict__ maskp,
                                float* __restrict__ cntp,
                                _Float16* __restrict__ nodein) {
  const int b = blockIdx.x;
  const int j = threadIdx.x;  // 64
  float o0 = obs[(b*4 + 0)*64 + j];
  float o1 = obs[(b*4 + 1)*64 + j];
  float o2 = obs[(b*4 + 2)*64 + j];
  float o3 = obs[(b*4 + 3)*64 + j];
  size_t bi = (size_t)b*64 + j;
  float* orow = o + bi*4;
  orow[0] = o0; orow[1] = o1; orow[2] = o2; orow[3] = o3;
  float s = fabsf(o0) + fabsf(o1) + fabsf(o2) + fabsf(o3);
  float m = (s != 0.0f) ? 1.0f : 0.0f;
  maskp[bi] = m;
  float c = m;
  #pragma unroll
  for (int off = 1; off < 64; off <<= 1) c += __shfl_xor(c, off);
  if (j == 0) cntp[b] = fmaxf(c, 1e-6f);
  _Float16* nrow = nodein + bi*NKP;
  nrow[0] = (_Float16)o0; nrow[1] = (_Float16)o1;
  nrow[2] = (_Float16)o2; nrow[3] = (_Float16)o3;
  nrow[516] = (_Float16)state[b*4 + 0];
  nrow[517] = (_Float16)state[b*4 + 1];
  nrow[518] = (_Float16)state[b*4 + 2];
  nrow[519] = (_Float16)state[b*4 + 3];
  for (int k2 = 520; k2 < 544; ++k2) nrow[k2] = (_Float16)0.0f;
}

// One block per b; thread c caches W1 row in regs, loops the 64 j's.
// e1w L2 traffic: 2048x16KB (R10) -> 32x16KB.
__global__ __launch_bounds__(512) void prep_uv16(
    const float* __restrict__ o,
    const float* __restrict__ e1w,
    const float* __restrict__ e1b,
    _Float16* __restrict__ u16,
    _Float16* __restrict__ v16) {
  const int b = blockIdx.x;      // 32
  const int c = threadIdx.x;     // 512
  const float* wr = e1w + c*8;
  float4 wa = *(const float4*)wr;
  float4 wb = *(const float4*)(wr + 4);
  float bias = e1b[c];
  for (int j = 0; j < 64; ++j) {
    const int bi = b*64 + j;
    const float* orow = o + (size_t)bi*4;
    float4 ov = *(const float4*)orow;
    float u = wa.x*ov.x + wa.y*ov.y + wa.z*ov.z + wa.w*ov.w + bias;
    float v = wb.x*ov.x + wb.y*ov.y + wb.z*ov.z + wb.w*ov.w;
    u16[(size_t)bi*NH + c] = (_Float16)u;
    v16[(size_t)bi*NH + c] = (_Float16)v;
  }
}

__global__ void prep_w16_kernel(const float* __restrict__ e2w,
                                const float* __restrict__ e3w,
                                const float* __restrict__ n2w,
                                const float* __restrict__ n1w,
                                _Float16* __restrict__ w2h,
                                _Float16* __restrict__ w3h,
                                _Float16* __restrict__ n2wh,
                                _Float16* __restrict__ n1wh) {
  int idx = blockIdx.x * blockDim.x + threadIdx.x;
  const int A = 512*512, Bc = 512*512, C = 256*512, Dn = 512*544;
  if (idx < A) {
    w2h[idx] = (_Float16)e2w[idx];
  } else if (idx < A + Bc) {
    int q = idx - A; w3h[q] = (_Float16)e3w[q];
  } else if (idx < A + Bc + C) {
    int q = idx - A - Bc; n2wh[q] = (_Float16)n2w[q];
  } else if (idx < A + Bc + C + Dn) {
    int q = idx - A - Bc - C;
    int n = q / 544, k = q % 544;
    n1wh[q] = (k < 520) ? (_Float16)n1w[n*520 + k] : (_Float16)0.0f;
  }
}

__global__ void prep_stfeat_kernel(const float* __restrict__ state,
                                   const float* __restrict__ lw,
                                   const float* __restrict__ lb,
                                   float* __restrict__ xfeat) {
  const int b = blockIdx.x, c = threadIdx.x;  // 512
  const float* s = state + b*4;
  const float* wr = lw + c*4;
  float hv = wr[0]*s[0] + wr[1]*s[1] + wr[2]*s[2] + wr[3]*s[3] + lb[c];
  xfeat[b*1024 + c] = fmaxf(hv, 0.0f);
}

// ----------------------------------------------------- edge (fused MLP) ----
// R4/R10 structure (best: edge ~184-190 us), three fixes:
//  1. H1 build with R3-proven slot-per-lane store pattern: lanes of an
//     8-group write 8 DISTINCT 16B slots of ONE row (conflict-free) instead
//     of same-slot/8-rows (8-way). Also fully coalesced 128B global reads.
//  2. af software pipeline: 32-MFMA block split in two 16-MFMA halves;
//     each half's 4 ds_reads issue before the PREVIOUS half's MFMAs, so
//     ds_read latency hides under MFMA issue. ~80 live VGPR, no spill.
//  3. s_setprio(1) around MFMA halves.
// One WG = 128 rows (2 (b,i) x 64 j), 8 waves, wave = all 128 j x 64 n.
// A-frag = H rows (LDS), B-frag = W rows (global/L2). D: row=j, col=n.
// H: [128][512] f16, byte(row,k) = (row*1024 + k*2) ^ ((row&7)<<4).

__device__ __forceinline__ void mlp_layer(const char* hb,
                                          const _Float16* __restrict__ wbase0,
                                          const float* __restrict__ biasp,
                                          int wcol, int lr, int lg,
                                          f32x4 acc[8][4]) {
  #pragma unroll
  for (int nt = 0; nt < 4; ++nt) {
    float bz = biasp[wcol + nt*16 + lr];
    #pragma unroll
    for (int mt = 0; mt < 8; ++mt) {
      acc[mt][nt][0] = bz; acc[mt][nt][1] = bz;
      acc[mt][nt][2] = bz; acc[mt][nt][3] = bz;
    }
  }
  const _Float16* bbase = wbase0 + (size_t)(wcol + lr)*NH + lg*8;
  f16x8 bfp[4];
  #pragma unroll
  for (int nt = 0; nt < 4; ++nt)
    bfp[nt] = *(const f16x8*)(bbase + nt*16*NH);

  // prefetch lo-half (mt 0..3) for kk=0
  f16x8 aflo[4];
  #pragma unroll
  for (int mt = 0; mt < 4; ++mt) {
    const int row = mt*16 + lr;
    aflo[mt] = *(const f16x8*)(hb + ((row*1024 + lg*16) ^ ((row & 7) << 4)));
  }

  for (int kk = 0; kk < 16; ++kk) {
    f16x8 bf[4];
    #pragma unroll
    for (int nt = 0; nt < 4; ++nt) bf[nt] = bfp[nt];
    if (kk < 15) {
      #pragma unroll
      for (int nt = 0; nt < 4; ++nt)
        bfp[nt] = *(const f16x8*)(bbase + nt*16*NH + (kk+1)*32);
    }
    // read hi-half (mt 4..7) of current kk, then MFMA lo-half
    f16x8 afhi[4];
    #pragma unroll
    for (int mt = 0; mt < 4; ++mt) {
      const int row = (mt + 4)*16 + lr;
      afhi[mt] = *(const f16x8*)(hb + ((row*1024 + kk*64 + lg*16) ^ ((row & 7) << 4)));
    }
    __builtin_amdgcn_s_setprio(1);
    #pragma unroll
    for (int mt = 0; mt < 4; ++mt)
      #pragma unroll
      for (int nt = 0; nt < 4; ++nt)
        acc[mt][nt] = __builtin_amdgcn_mfma_f32_16x16x32_f16(aflo[mt], bf[nt], acc[mt][nt], 0, 0, 0);
    __builtin_amdgcn_s_setprio(0);
    // read lo-half of next kk, then MFMA hi-half
    f16x8 aflon[4];
    if (kk < 15) {
      #pragma unroll
      for (int mt = 0; mt < 4; ++mt) {
        const int row = mt*16 + lr;
        aflon[mt] = *(const f16x8*)(hb + ((row*1024 + (kk+1)*64 + lg*16) ^ ((row & 7) << 4)));
      }
    }
    __builtin_amdgcn_s_setprio(1);
    #pragma unroll
    for (int mt = 0; mt < 4; ++mt)
      #pragma unroll
      for (int nt = 0; nt < 4; ++nt)
        acc[mt + 4][nt] = __builtin_amdgcn_mfma_f32_16x16x32_f16(afhi[mt], bf[nt], acc[mt + 4][nt], 0, 0, 0);
    __builtin_amdgcn_s_setprio(0);
    #pragma unroll
    for (int mt = 0; mt < 4; ++mt) aflo[mt] = aflon[mt];
  }
}

__global__ __launch_bounds__(512, 1) void edge_fused(
    const _Float16* __restrict__ u16, const _Float16* __restrict__ v16,
    const _Float16* __restrict__ w2h, const _Float16* __restrict__ w3h,
    const float* __restrict__ e2b, const float* __restrict__ e3b,
    const float* __restrict__ maskp, const float* __restrict__ cntp,
    const float* __restrict__ lng, const float* __restrict__ lnb,
    _Float16* __restrict__ nodein) {
  __shared__ __align__(16) char lds[131072];
  __shared__ float em_s[64];
  __shared__ float red_s[16];
  __shared__ float stat_s[2];

  const int t = threadIdx.x;
  const int bi0 = blockIdx.x * 2;      // two consecutive (b,i), same b
  const int b = bi0 >> 6;
  const int w = t >> 6, l = t & 63, lr = l & 15, lg = l >> 4;
  const int wcol = w * 64;

  if (t < 64) em_s[t] = maskp[(size_t)b*64 + t];

  // ---- build H1 (conflict-free): lane t -> row t>>3, 16B slot t&7.
  // Per e-iter: 8-lane group writes 8 distinct slots of one row.
  {
    const int jrow = t >> 3;    // j 0..63
    const int slot = t & 7;
    const _Float16* vrow = v16 + ((size_t)(b*64 + jrow))*NH;
    const _Float16* u0p  = u16 + (size_t)bi0*NH;
    const _Float16* u1p  = u16 + (size_t)(bi0 + 1)*NH;
    #pragma unroll
    for (int e = 0; e < 8; ++e) {
      const int kelem = e*64 + slot*8;
      f16x8 vv = *(const f16x8*)(vrow + kelem);
      f16x8 u0 = *(const f16x8*)(u0p + kelem);
      f16x8 u1 = *(const f16x8*)(u1p + kelem);
      f16x8 h0, h1;
      #pragma unroll
      for (int q = 0; q < 8; ++q) {
        _Float16 x0 = u0[q] + vv[q];
        _Float16 x1 = u1[q] + vv[q];
        h0[q] = x0 > (_Float16)0 ? x0 : (_Float16)0;
        h1[q] = x1 > (_Float16)0 ? x1 : (_Float16)0;
      }
      const int bc = kelem*2;
      const int r1 = 64 + jrow;
      *(f16x8*)(lds + ((jrow*1024 + bc) ^ ((jrow & 7) << 4))) = h0;
      *(f16x8*)(lds + ((r1*1024 + bc) ^ ((r1 & 7) << 4))) = h1;
    }
  }
  __syncthreads();

  f32x4 acc[8][4];   // [mt][nt]; j-row = mt*16 + lg*4 + r, n = wcol+nt*16+lr

  // ---- layer 2: acc = H1 @ W2^T + b2
  mlp_layer(lds, w2h, e2b, wcol, lr, lg, acc);
  __syncthreads();   // all waves done reading H1

  // ---- H2 = relu(acc) overwrites the same LDS buffer (same layout)
  #pragma unroll
  for (int mt = 0; mt < 8; ++mt)
    #pragma unroll
    for (int nt = 0; nt < 4; ++nt)
      #pragma unroll
      for (int r = 0; r < 4; ++r) {
        int row = mt*16 + lg*4 + r;
        int cc = wcol + nt*16 + lr;
        *(_Float16*)(lds + ((row*1024 + cc*2) ^ ((row & 7) << 4))) =
            (_Float16)fmaxf(acc[mt][nt][r], 0.0f);
      }
  __syncthreads();   // H2 complete

  // ---- layer 3: acc = H2 @ W3^T + b3
  mlp_layer(lds, w3h, e3b, wcol, lr, lg, acc);

  // ---- relu + mask-weighted sum over j; rows 0-63 -> bi0, 64-127 -> bi0+1
  float csum[2][4] = {{0.f,0.f,0.f,0.f},{0.f,0.f,0.f,0.f}};
  #pragma unroll
  for (int mt = 0; mt < 8; ++mt) {
    const int g = mt >> 2;
    float em0 = em_s[(mt&3)*16 + lg*4 + 0];
    float em1 = em_s[(mt&3)*16 + lg*4 + 1];
    float em2 = em_s[(mt&3)*16 + lg*4 + 2];
    float em3 = em_s[(mt&3)*16 + lg*4 + 3];
    #pragma unroll
    for (int nt = 0; nt < 4; ++nt) {
      csum[g][nt] += em0 * fmaxf(acc[mt][nt][0], 0.f)
                   + em1 * fmaxf(acc[mt][nt][1], 0.f)
                   + em2 * fmaxf(acc[mt][nt][2], 0.f)
                   + em3 * fmaxf(acc[mt][nt][3], 0.f);
    }
  }
  #pragma unroll
  for (int g = 0; g < 2; ++g)
    #pragma unroll
    for (int nt = 0; nt < 4; ++nt) {
      csum[g][nt] += __shfl_xor(csum[g][nt], 16);
      csum[g][nt] += __shfl_xor(csum[g][nt], 32);
    }
  float cnt = cntp[b];
  __syncthreads();   // done with H2 reads; reuse lds as agg[2][512]
  float* aggs = (float*)lds;
  if (lg == 0) {
    #pragma unroll
    for (int g = 0; g < 2; ++g) {
      int big = bi0 + g;
      float sc = em_s[big & 63] / cnt;
      #pragma unroll
      for (int nt = 0; nt < 4; ++nt)
        aggs[g*512 + wcol + nt*16 + lr] = csum[g][nt] * sc;
    }
  }
  __syncthreads();

  // ---- LayerNorm (both rows) + nodein write
  for (int g = 0; g < 2; ++g) {
    float a = aggs[g*512 + t];
    float s1 = a, s2 = a * a;
    #pragma unroll
    for (int off = 1; off < 64; off <<= 1) {
      s1 += __shfl_xor(s1, off);
      s2 += __shfl_xor(s2, off);
    }
    if (l == 0) { red_s[w] = s1; red_s[8 + w] = s2; }
    __syncthreads();
    if (t == 0) {
      float S1 = 0.f, S2 = 0.f;
      #pragma unroll
      for (int q = 0; q < 8; ++q) { S1 += red_s[q]; S2 += red_s[8 + q]; }
      float mean = S1 * (1.0f/512.0f);
      float var = S2 * (1.0f/512.0f) - mean * mean;
      stat_s[0] = mean;
      stat_s[1] = rsqrtf(var + 1e-5f);
    }
    __syncthreads();
    float nrm = (a - stat_s[0]) * stat_s[1] * lng[t] + lnb[t];
    nodein[(size_t)(bi0 + g)*NKP + 4 + t] = (_Float16)nrm;
    __syncthreads();   // protect red_s/stat_s before next g
  }
}

// ---------------------------------------------------------------- node ----

template <int RELU16>
__global__ __launch_bounds__(256) void node_gemm(
    const _Float16* __restrict__ A, const _Float16* __restrict__ Bw,
    const float* __restrict__ bias, void* __restrict__ outp,
    int Ka, int ldo) {
  const int t = threadIdx.x;
  const int w = t >> 6, l = t & 63, lr = l & 15, lg = l >> 4;
  const int m0 = blockIdx.x * 64;
  const int col = blockIdx.y * 64 + w*16 + lr;
  f32x4 acc[4];
  float bz = bias[col];
  #pragma unroll
  for (int mt = 0; mt < 4; ++mt) {
    acc[mt][0] = bz; acc[mt][1] = bz; acc[mt][2] = bz; acc[mt][3] = bz;
  }
  const _Float16* bptr = Bw + (size_t)col*Ka + lg*8;
  const _Float16* aptr = A + (size_t)(m0 + lr)*Ka + lg*8;
  const int nkk = Ka >> 5;
  for (int kk = 0; kk < nkk; ++kk) {
    f16x8 bf = *(const f16x8*)(bptr + kk*32);
    #pragma unroll
    for (int mt = 0; mt < 4; ++mt) {
      f16x8 af = *(const f16x8*)(aptr + ((size_t)mt*16)*Ka + kk*32);
      acc[mt] = __builtin_amdgcn_mfma_f32_16x16x32_f16(af, bf, acc[mt], 0, 0, 0);
    }
  }
  #pragma unroll
  for (int mt = 0; mt < 4; ++mt)
    #pragma unroll
    for (int r = 0; r < 4; ++r) {
      int row = m0 + mt*16 + lg*4 + r;
      float vv = acc[mt][r];
      if (RELU16)
        ((_Float16*)outp)[(size_t)row*ldo + col] = (_Float16)fmaxf(vv, 0.f);
      else
        ((float*)outp)[(size_t)row*ldo + col] = vv;
    }
}

// ----------------------------------------------------------- pool/heads ----

__global__ __launch_bounds__(256) void pool_kernel(
    const float* __restrict__ nodeout, const float* __restrict__ maskp,
    const float* __restrict__ cntp, float* __restrict__ xfeat) {
  const int b = blockIdx.x;
  const int c = threadIdx.x;  // 256
  float sum = 0.f, mx = -1e9f;
  for (int i = 0; i < 64; ++i) {
    float m = maskp[b*64 + i];
    float v = nodeout[((size_t)(b*64 + i))*256 + c];
    sum += m * v;
    mx = fmaxf(mx, (m != 0.f) ? v : -1e9f);
  }
  xfeat[b*1024 + 512 + c] = sum / cntp[b];
  xfeat[b*1024 + 768 + c] = mx;
}

// heads stage 1: partial dots over a 256-wide K slice.
__global__ __launch_bounds__(256) void heads_g1(
    const float* __restrict__ xfeat,
    const float* __restrict__ mu1w, const float* __restrict__ s1w,
    float* __restrict__ part) {
  __shared__ __align__(16) float xs[256];
  const int b = blockIdx.x, h = blockIdx.y, ks = blockIdx.z;
  const int t = threadIdx.x;
  xs[t] = xfeat[b*1024 + ks*256 + t];
  __syncthreads();
  const float* wr = (h ? s1w : mu1w) + (size_t)t*1024 + ks*256;
  float a = 0.f;
  #pragma unroll 8
  for (int k = 0; k < 256; k += 4) {
    float4 ww = *(const float4*)(wr + k);
    float4 xx = *(const float4*)(xs + k);
    a += ww.x*xx.x + ww.y*xx.y + ww.z*xx.z + ww.w*xx.w;
  }
  part[(((size_t)(b*2 + h))*256 + t)*4 + ks] = a;
}

// heads stage 2+3.
__global__ __launch_bounds__(256) void heads_g23(
    const float* __restrict__ part,
    const float* __restrict__ mu1b, const float* __restrict__ s1b,
    const float* __restrict__ mu2w, const float* __restrict__ mu2b,
    const float* __restrict__ s2w, const float* __restrict__ s2b,
    const float* __restrict__ mu3w, const float* __restrict__ mu3b,
    const float* __restrict__ s3w, const float* __restrict__ s3b,
    float* __restrict__ outp) {
  __shared__ __align__(16) float h1s[256];
  __shared__ __align__(16) float h2s[128];
  const int b = blockIdx.x, h = blockIdx.y;
  const int t = threadIdx.x;
  {
    float4 pp = *(const float4*)(part + (((size_t)(b*2 + h))*256 + t)*4);
    float a = pp.x + pp.y + pp.z + pp.w + (h ? s1b : mu1b)[t];
    h1s[t] = fmaxf(a, 0.f);
  }
  __syncthreads();
  {
    const int o = t >> 1, half = t & 1;
    const float* wr = (h ? s2w : mu2w) + (size_t)o*256 + half*128;
    const float* hp = h1s + half*128;
    float a = 0.f;
    #pragma unroll 8
    for (int k = 0; k < 128; k += 4) {
      float4 ww = *(const float4*)(wr + k);
      float4 hh = *(const float4*)(hp + k);
      a += ww.x*hh.x + ww.y*hh.y + ww.z*hh.z + ww.w*hh.w;
    }
    a += __shfl_xor(a, 1);
    if (half == 0) h2s[o] = fmaxf(a + (h ? s2b : mu2b)[o], 0.f);
  }
  __syncthreads();
  if (t < 64) {
    const int o = t >> 5, lane = t & 31;
    const float* wr = (h ? s3w : mu3w) + o*128 + lane*4;
    const float* hp = h2s + lane*4;
    float4 ww = *(const float4*)wr;
    float4 hh = *(const float4*)hp;
    float a = ww.x*hh.x + ww.y*hh.y + ww.z*hh.z + ww.w*hh.w;
    #pragma unroll
    for (int off = 1; off < 32; off <<= 1) a += __shfl_xor(a, off);
    if (lane == 0) {
      a += (h ? s3b : mu3b)[o];
      if (h == 0) {
        outp[b*2 + o] = a;
      } else {
        float spv = (a > 0.f) ? (a + log1pf(expf(-a))) : log1pf(expf(a));
        outp[64 + b*2 + o] = fminf(fmaxf(spv + 0.001f, 0.1f), 2.0f);
      }
    }
  }
}

// --------------------------------------------------------------- launch ----

extern "C" void kernel_launch(void* const* d_in, const int* in_sizes, int n_in,
                              void* d_out, int out_size, void* d_ws, size_t ws_size,
                              hipStream_t stream) {
  const float* state  = (const float*)d_in[0];
  const float* obs    = (const float*)d_in[1];
  const float* layerw = (const float*)d_in[2];
  const float* layerb = (const float*)d_in[3];
  const float* e1w    = (const float*)d_in[4];
  const float* e1b    = (const float*)d_in[5];
  const float* e2w    = (const float*)d_in[6];
  const float* e2b    = (const float*)d_in[7];
  const float* e3w    = (const float*)d_in[8];
  const float* e3b    = (const float*)d_in[9];
  const float* lng    = (const float*)d_in[10];
  const float* lnb    = (const float*)d_in[11];
  const float* n1w    = (const float*)d_in[12];
  const float* n1b    = (const float*)d_in[13];
  const float* n2w    = (const float*)d_in[14];
  const float* n2b    = (const float*)d_in[15];
  const float* mu1w   = (const float*)d_in[16];
  const float* mu1b   = (const float*)d_in[17];
  const float* mu2w   = (const float*)d_in[18];
  const float* mu2b   = (const float*)d_in[19];
  const float* mu3w   = (const float*)d_in[20];
  const float* mu3b   = (const float*)d_in[21];
  const float* s1w    = (const float*)d_in[22];
  const float* s1b    = (const float*)d_in[23];
  const float* s2w    = (const float*)d_in[24];
  const float* s2b    = (const float*)d_in[25];
  const float* s3w    = (const float*)d_in[26];
  const float* s3b    = (const float*)d_in[27];
  float* outp = (float*)d_out;

  char* p = (char*)d_ws;
  auto alloc = [&](size_t bytes) {
    char* r = p;
    p += (bytes + 255) & ~(size_t)255;
    return r;
  };
  float*    o       = (float*)alloc((size_t)2048*4*4);
  float*    maskp   = (float*)alloc((size_t)2048*4);
  float*    cntp    = (float*)alloc((size_t)32*4);
  _Float16* u16     = (_Float16*)alloc((size_t)2048*512*2);
  _Float16* v16     = (_Float16*)alloc((size_t)2048*512*2);
  _Float16* w2h     = (_Float16*)alloc((size_t)512*512*2);
  _Float16* w3h     = (_Float16*)alloc((size_t)512*512*2);
  _Float16* nodein  = (_Float16*)alloc((size_t)2048*544*2);
  _Float16* n1wh    = (_Float16*)alloc((size_t)512*544*2);
  _Float16* n2wh    = (_Float16*)alloc((size_t)256*512*2);
  _Float16* nodeh   = (_Float16*)alloc((size_t)2048*512*2);
  float*    nodeout = (float*)alloc((size_t)2048*256*4);
  float*    xfeat   = (float*)alloc((size_t)32*1024*4);
  float*    hpart   = (float*)alloc((size_t)32*2*256*4*4);

  prep_obs_kernel<<<32, 64, 0, stream>>>(obs, state, o, maskp, cntp, nodein);
  prep_uv16<<<32, 512, 0, stream>>>(o, e1w, e1b, u16, v16);
  prep_w16_kernel<<<3648, 256, 0, stream>>>(e2w, e3w, n2w, n1w, w2h, w3h, n2wh, n1wh);
  prep_stfeat_kernel<<<32, 512, 0, stream>>>(state, layerw, layerb, xfeat);

  edge_fused<<<1024, 512, 0, stream>>>(u16, v16, w2h, w3h, e2b, e3b,
                                       maskp, cntp, lng, lnb, nodein);

  node_gemm<1><<<dim3(32, 8), 256, 0, stream>>>(nodein, n1wh, n1b, (void*)nodeh, 544, 512);
  node_gemm<0><<<dim3(32, 4), 256, 0, stream>>>(nodeh, n2wh, n2b, (void*)nodeout, 512, 256);
  pool_kernel<<<32, 256, 0, stream>>>(nodeout, maskp, cntp, xfeat);
  heads_g1<<<dim3(32, 2, 4), 256, 0, stream>>>(xfeat, mu1w, s1w, hpart);
  heads_g23<<<dim3(32, 2), 256, 0, stream>>>(hpart, mu1b, s1b, mu2w, mu2b,
                                             s2w, s2b, mu3w, mu3b, s3w, s3b, outp);
}